// Round 10
// baseline (327.869 us; speedup 1.0000x reference)
//
#include <hip/hip_runtime.h>

#define N_NODES 100000
#define N_EDGES 1250000
#define D 64
#define ED 32
#define CAP 40          // bucket capacity; Poisson(12.5) max-deg ~ 30
#define OVF_CAP 131072

typedef unsigned int uint;
typedef unsigned short ushort;

__device__ __forceinline__ uint bfr(float f) {
    uint u = __float_as_uint(f);
    return (u + 0x7FFFu + ((u >> 16) & 1u)) >> 16;
}
__device__ __forceinline__ float bfu(ushort s) { return __uint_as_float(((uint)s) << 16); }

// ---------------- bucket scatter: erec[c*CAP+pos] = {row, e}; overflow to list ----------------

__global__ void __launch_bounds__(256) scatter_bucket_k(const int* __restrict__ row,
                                                        const int* __restrict__ col,
                                                        int* __restrict__ cursor,   // zeroed; becomes deg
                                                        int2* __restrict__ erec,
                                                        int4* __restrict__ ovf,
                                                        int* __restrict__ ovfcnt) {
    int i = blockIdx.x * blockDim.x + threadIdx.x;
    const int stride = gridDim.x * blockDim.x;
    for (int e = i; e < N_EDGES; e += stride) {
        const int c = col[e];
        const int r = row[e];
        const int pos = atomicAdd(&cursor[c], 1);
        if (pos < CAP) {
            erec[(size_t)c * CAP + pos] = make_int2(r, e);
        } else {
            const int o = atomicAdd(ovfcnt, 1);
            if (o < OVF_CAP) ovf[o] = make_int4(c, r, e, 0);
        }
    }
}

// ---------------- xl16 = bf16(x @ lw^T) (blocks 0..1023) | Cmat,lwb (block 1024) ----------------

__global__ void __launch_bounds__(256) xl16_combine_k(const float* __restrict__ x,
                                                      const float* __restrict__ lw,
                                                      ushort* __restrict__ xl,
                                                      const float* __restrict__ ew,
                                                      const float* __restrict__ eb,
                                                      float* __restrict__ Cmat,
                                                      float* __restrict__ lwb) {
    const int bid = blockIdx.x;
    if (bid < 1024) {
        const int lane = threadIdx.x & 63;
        const int wid  = bid * 4 + (threadIdx.x >> 6);
        const int nw   = 1024 * 4;

        float w[D];
        const float4* lw4 = (const float4*)(lw + (size_t)lane * D);
#pragma unroll
        for (int q = 0; q < D / 4; ++q) {
            const float4 v = lw4[q];
            w[4*q+0] = v.x; w[4*q+1] = v.y; w[4*q+2] = v.z; w[4*q+3] = v.w;
        }
        for (int n = wid; n < N_NODES; n += nw) {
            const float4* xx = (const float4*)(x + (size_t)n * D);
            float d0 = 0.f, d1 = 0.f;
#pragma unroll
            for (int q = 0; q < D / 8; ++q) {
                const float4 v0 = xx[q];
                const float4 v1 = xx[q + 8];
                d0 = fmaf(v0.x, w[4*q+0], d0);  d0 = fmaf(v0.y, w[4*q+1], d0);
                d0 = fmaf(v0.z, w[4*q+2], d0);  d0 = fmaf(v0.w, w[4*q+3], d0);
                d1 = fmaf(v1.x, w[4*q+32], d1); d1 = fmaf(v1.y, w[4*q+33], d1);
                d1 = fmaf(v1.z, w[4*q+34], d1); d1 = fmaf(v1.w, w[4*q+35], d1);
            }
            xl[(size_t)n * D + lane] = (ushort)bfr(d0 + d1);
        }
    } else {
        for (int idx = threadIdx.x; idx < D * ED; idx += 256) {
            const int d = idx >> 5, j = idx & 31;
            float s = 0.f;
#pragma unroll
            for (int k = 0; k < D; ++k) s = fmaf(lw[d * D + k], ew[k * ED + j], s);
            Cmat[idx] = s;
        }
        if (threadIdx.x < D) {
            float s = 0.f;
#pragma unroll
            for (int k = 0; k < D; ++k) s = fmaf(lw[threadIdx.x * D + k], eb[k], s);
            lwb[threadIdx.x] = s;
        }
    }
}

// ---------------- paired aggregation + epilogue (2 nodes per wave-iteration) ----------------
// out[n][d] = inv*( segsum(xl[row]) + Cmat·segsum(ea) )[d] + [deg>0]*lwb[d] + lb[d]
// Two independent nodes' load rounds interleave -> ~16 VMEM in flight per wave.

__global__ void __launch_bounds__(256) agg_pair_k(const ushort* __restrict__ xl,
                                                  const float* __restrict__ ea,
                                                  const int* __restrict__ deg_,
                                                  const int2* __restrict__ erec,
                                                  const int4* __restrict__ ovf,
                                                  const int* __restrict__ ovfcnt,
                                                  const float* __restrict__ Cmat,
                                                  const float* __restrict__ lwb,
                                                  const float* __restrict__ lb,
                                                  float* __restrict__ out) {
    const int lane = threadIdx.x & 63;
    const int wid  = blockIdx.x * (blockDim.x >> 6) + (threadIdx.x >> 6);
    const int nw   = gridDim.x * (blockDim.x >> 6);

    const float lwbl = lwb[lane];
    const float lbl  = lb[lane];
    const float4* cm4 = (const float4*)(Cmat + (size_t)lane * ED);  // L1-hot
    const int novf = min(*ovfcnt, OVF_CAP);
    const int NH = N_NODES / 2;

    for (int p = wid; p < NH; p += nw) {
        const int nA = p, nB = p + NH;
        const int degA = deg_[nA], degB = deg_[nB];
        const int dA = min(degA, CAP), dB = min(degB, CAP);

        float axA[8] = {0,0,0,0,0,0,0,0}, axB[8] = {0,0,0,0,0,0,0,0};
        float aeA[8] = {0,0,0,0,0,0,0,0}, aeB[8] = {0,0,0,0,0,0,0,0};

        int2 recA = make_int2(0, 0), recB = make_int2(0, 0);
        if (dA > 0) recA = erec[(size_t)nA * CAP + min(lane, dA - 1)];   // coalesced
        if (dB > 0) recB = erec[(size_t)nB * CAP + min(lane, dB - 1)];

        // ---- xl gathers: interleaved full rounds of 8 per node ----
        const int fullA = dA & ~7, fullB = dB & ~7;
        const int fullM = max(fullA, fullB);
        for (int k = 0; k < fullM; k += 8) {
            float vA[8], vB[8];
            const bool doA = k < fullA, doB = k < fullB;   // wave-uniform
            if (doA) {
#pragma unroll
                for (int i = 0; i < 8; ++i)
                    vA[i] = bfu(xl[(size_t)__shfl(recA.x, k + i) * D + lane]);
            }
            if (doB) {
#pragma unroll
                for (int i = 0; i < 8; ++i)
                    vB[i] = bfu(xl[(size_t)__shfl(recB.x, k + i) * D + lane]);
            }
            if (doA) {
#pragma unroll
                for (int i = 0; i < 8; ++i) axA[i] += vA[i];
            }
            if (doB) {
#pragma unroll
                for (int i = 0; i < 8; ++i) axB[i] += vB[i];
            }
        }
        // ---- xl tails: both predicated rounds issue before either consumes ----
        {
            float vA[8], vB[8];
            const bool tA = fullA < dA, tB = fullB < dB;
            if (tA) {
#pragma unroll
                for (int i = 0; i < 8; ++i)
                    vA[i] = bfu(xl[(size_t)__shfl(recA.x, min(fullA + i, dA - 1)) * D + lane]);
            }
            if (tB) {
#pragma unroll
                for (int i = 0; i < 8; ++i)
                    vB[i] = bfu(xl[(size_t)__shfl(recB.x, min(fullB + i, dB - 1)) * D + lane]);
            }
            if (tA) {
#pragma unroll
                for (int i = 0; i < 8; ++i) axA[i] += (fullA + i < dA) ? vA[i] : 0.f;
            }
            if (tB) {
#pragma unroll
                for (int i = 0; i < 8; ++i) axB[i] += (fullB + i < dB) ? vB[i] : 0.f;
            }
        }

        // ---- ea reads: half-wave per edge, interleaved rounds of 8 per node ----
        const int npA = (dA + 1) >> 1, npB = (dB + 1) >> 1;   // <= 20
        const int npM = max(npA, npB);
        const int half = lane >> 5;
        for (int t = 0; t < npM; t += 8) {
            float vA[8], vB[8];
            int pA[8], pB[8];
            const bool doA = t < npA, doB = t < npB;
            if (doA) {
#pragma unroll
                for (int i = 0; i < 8; ++i) {
                    const int pr = min(t + i, npA - 1);
                    const int sl = min(2 * pr + half, dA - 1);
                    pA[i] = (t + i < npA) && (2 * pr + half < dA);
                    vA[i] = ea[(size_t)__shfl(recA.y, sl) * ED + (lane & 31)];
                }
            }
            if (doB) {
#pragma unroll
                for (int i = 0; i < 8; ++i) {
                    const int pr = min(t + i, npB - 1);
                    const int sl = min(2 * pr + half, dB - 1);
                    pB[i] = (t + i < npB) && (2 * pr + half < dB);
                    vB[i] = ea[(size_t)__shfl(recB.y, sl) * ED + (lane & 31)];
                }
            }
            if (doA) {
#pragma unroll
                for (int i = 0; i < 8; ++i) aeA[i] += pA[i] ? vA[i] : 0.f;
            }
            if (doB) {
#pragma unroll
                for (int i = 0; i < 8; ++i) aeB[i] += pB[i] ? vB[i] : 0.f;
            }
        }

        // ---- overflow edges (correctness path; empty in practice) ----
        if (novf > 0) {
            for (int o = 0; o < novf; ++o) {
                const int4 v = ovf[o];
                if (v.x == nA) {
                    axA[0] += bfu(xl[(size_t)v.y * D + lane]);
                    if (lane < ED) aeA[0] += ea[(size_t)v.z * ED + lane];
                }
                if (v.x == nB) {
                    axB[0] += bfu(xl[(size_t)v.y * D + lane]);
                    if (lane < ED) aeB[0] += ea[(size_t)v.z * ED + lane];
                }
            }
        }

        // ---- epilogue A ----
        {
            float axs = ((axA[0]+axA[1])+(axA[2]+axA[3])) + ((axA[4]+axA[5])+(axA[6]+axA[7]));
            float aes = ((aeA[0]+aeA[1])+(aeA[2]+aeA[3])) + ((aeA[4]+aeA[5])+(aeA[6]+aeA[7]));
            aes += __shfl_xor(aes, 32);
            float zd = axs;
#pragma unroll
            for (int q = 0; q < ED / 4; ++q) {
                const float4 wv = cm4[q];
                zd = fmaf(__shfl(aes, 4*q+0), wv.x, zd);
                zd = fmaf(__shfl(aes, 4*q+1), wv.y, zd);
                zd = fmaf(__shfl(aes, 4*q+2), wv.z, zd);
                zd = fmaf(__shfl(aes, 4*q+3), wv.w, zd);
            }
            const float inv = 1.f / fmaxf((float)degA, 1.f);
            out[(size_t)nA * D + lane] = fmaf(inv, zd, (degA > 0 ? lwbl : 0.f) + lbl);
        }
        // ---- epilogue B ----
        {
            float axs = ((axB[0]+axB[1])+(axB[2]+axB[3])) + ((axB[4]+axB[5])+(axB[6]+axB[7]));
            float aes = ((aeB[0]+aeB[1])+(aeB[2]+aeB[3])) + ((aeB[4]+aeB[5])+(aeB[6]+aeB[7]));
            aes += __shfl_xor(aes, 32);
            float zd = axs;
#pragma unroll
            for (int q = 0; q < ED / 4; ++q) {
                const float4 wv = cm4[q];
                zd = fmaf(__shfl(aes, 4*q+0), wv.x, zd);
                zd = fmaf(__shfl(aes, 4*q+1), wv.y, zd);
                zd = fmaf(__shfl(aes, 4*q+2), wv.z, zd);
                zd = fmaf(__shfl(aes, 4*q+3), wv.w, zd);
            }
            const float inv = 1.f / fmaxf((float)degB, 1.f);
            out[(size_t)nB * D + lane] = fmaf(inv, zd, (degB > 0 ? lwbl : 0.f) + lbl);
        }
    }
}

// ---------------- tier C (tiny ws): atomic version ----------------

__global__ void __launch_bounds__(256) edge_scatter_fb(
    const float* __restrict__ x, const int* __restrict__ ei,
    const float* __restrict__ ea, const float* __restrict__ ew,
    const float* __restrict__ eb, float* __restrict__ agg, float* __restrict__ deg) {
    const int lane = threadIdx.x & 63;
    const int wid  = blockIdx.x * (blockDim.x >> 6) + (threadIdx.x >> 6);
    const int nw   = gridDim.x * (blockDim.x >> 6);
    float w[ED];
#pragma unroll
    for (int k = 0; k < ED; ++k) w[k] = ew[lane * ED + k];
    const float b = eb[lane];
    for (int e = wid; e < N_EDGES; e += nw) {
        const int r = ei[e];
        const int c = ei[N_EDGES + e];
        const float4* ea4 = (const float4*)(ea + (size_t)e * ED);
        float acc = b;
#pragma unroll
        for (int q = 0; q < ED / 4; ++q) {
            float4 v = ea4[q];
            acc = fmaf(v.x, w[4*q+0], acc); acc = fmaf(v.y, w[4*q+1], acc);
            acc = fmaf(v.z, w[4*q+2], acc); acc = fmaf(v.w, w[4*q+3], acc);
        }
        acc += x[(size_t)r * D + lane];
        atomicAdd(&agg[(size_t)c * D + lane], acc);
        if (lane == 0) atomicAdd(&deg[c], 1.0f);
    }
}

__global__ void __launch_bounds__(256) node_linear_fb(
    float* __restrict__ agg, const float* __restrict__ deg,
    const float* __restrict__ lw, const float* __restrict__ lb) {
    const int lane = threadIdx.x & 63;
    const int wid  = blockIdx.x * (blockDim.x >> 6) + (threadIdx.x >> 6);
    const int nw   = gridDim.x * (blockDim.x >> 6);
    float w[D];
#pragma unroll
    for (int k = 0; k < D; ++k) w[k] = lw[lane * D + k];
    const float b = lb[lane];
    for (int n = wid; n < N_NODES; n += nw) {
        const float inv = 1.0f / fmaxf(deg[n], 1.0f);
        const float4* a4 = (const float4*)(agg + (size_t)n * D);
        float dot = 0.0f;
#pragma unroll
        for (int q = 0; q < D / 4; ++q) {
            float4 v = a4[q];
            dot = fmaf(v.x, w[4*q+0], dot); dot = fmaf(v.y, w[4*q+1], dot);
            dot = fmaf(v.z, w[4*q+2], dot); dot = fmaf(v.w, w[4*q+3], dot);
        }
        agg[(size_t)n * D + lane] = fmaf(inv, dot, b);
    }
}

// ---------------- launch ----------------

extern "C" void kernel_launch(void* const* d_in, const int* in_sizes, int n_in,
                              void* d_out, int out_size, void* d_ws, size_t ws_size,
                              hipStream_t stream) {
    const float* x  = (const float*)d_in[0];
    const int*   ei = (const int*)d_in[1];     // [2][E]: rows then cols
    const float* ea = (const float*)d_in[2];
    const float* lw = (const float*)d_in[3];
    const float* lb = (const float*)d_in[4];
    const float* ew = (const float*)d_in[5];
    const float* eb = (const float*)d_in[6];
    const int* row = ei;
    const int* col = ei + N_EDGES;

    char* ws = (char*)d_ws;
    float* zout = (float*)d_out;

    // ws layout (~47.3 MB)
    const size_t W_EREC = 0;                                   // N*CAP int2 = 32,000,000
    const size_t W_OVF  = (size_t)N_NODES * CAP * 8;           // OVF_CAP int4 = 2,097,152
    const size_t W_XL   = W_OVF + (size_t)OVF_CAP * 16;        // N*64 ushort = 12,800,000
    const size_t W_CNT  = W_XL + (size_t)N_NODES * D * 2;      //    400,000
    const size_t W_OVFC = W_CNT + (size_t)N_NODES * 4;         //         16
    const size_t W_CMAT = W_OVFC + 16;                         //      8,192
    const size_t W_LWB  = W_CMAT + D * ED * 4;                 //        256
    const size_t REQ    = W_LWB + D * 4;

    if (ws_size >= REQ) {
        int2*   erec = (int2*)(ws + W_EREC);
        int4*   ovf  = (int4*)(ws + W_OVF);
        ushort* xl   = (ushort*)(ws + W_XL);
        int*    cnt  = (int*)(ws + W_CNT);
        int*    ovfc = (int*)(ws + W_OVFC);
        float*  Cmat = (float*)(ws + W_CMAT);
        float*  lwbv = (float*)(ws + W_LWB);

        hipMemsetAsync(cnt, 0, (size_t)N_NODES * sizeof(int) + 16, stream);
        scatter_bucket_k<<<2048, 256, 0, stream>>>(row, col, cnt, erec, ovf, ovfc);
        xl16_combine_k  <<<1025, 256, 0, stream>>>(x, lw, xl, ew, eb, Cmat, lwbv);
        agg_pair_k      <<<2048, 256, 0, stream>>>(xl, ea, cnt, erec, ovf, ovfc,
                                                   Cmat, lwbv, lb, zout);
    } else {
        float* deg = (float*)d_ws;
        hipMemsetAsync(zout, 0, (size_t)N_NODES * D * sizeof(float), stream);
        hipMemsetAsync(deg, 0, (size_t)N_NODES * sizeof(float), stream);
        edge_scatter_fb<<<2048, 256, 0, stream>>>(x, ei, ea, ew, eb, zout, deg);
        node_linear_fb <<<1024, 256, 0, stream>>>(zout, deg, lw, lb);
    }
}

// Round 11
// 316.002 us; speedup vs baseline: 1.0376x; 1.0376x over previous
//
#include <hip/hip_runtime.h>

#define N_NODES 100000
#define N_EDGES 1250000
#define D 64
#define ED 32
#define CAP 32          // bucket = 32 slots * 8B = 256B, line-aligned; P(deg>32)~1e-8/node
#define OVF_CAP 131072

typedef unsigned int uint;
typedef unsigned short ushort;

__device__ __forceinline__ uint bfr(float f) {
    uint u = __float_as_uint(f);
    return (u + 0x7FFFu + ((u >> 16) & 1u)) >> 16;
}
__device__ __forceinline__ uint pk(float a, float b) { return bfr(a) | (bfr(b) << 16); }
__device__ __forceinline__ float bfu(ushort s) { return __uint_as_float(((uint)s) << 16); }
__device__ __forceinline__ float bflo(uint v) { return __uint_as_float(v << 16); }
__device__ __forceinline__ float bfhi(uint v) { return __uint_as_float(v & 0xffff0000u); }

// ---------------- fused scatter + ea->bf16 conv (phase-sequential per block) ----------------
// Phase 1 (atomic-latency-bound) and phase 2 (BW-bound streaming) overlap machine-wide:
// all blocks resident; conv fills scatter's latency stalls + warms eab into L3 for agg.

__global__ void __launch_bounds__(256) scatconv_k(const int* __restrict__ row,
                                                  const int* __restrict__ col,
                                                  int* __restrict__ cursor,   // zeroed; becomes deg
                                                  int2* __restrict__ erec,
                                                  int4* __restrict__ ovf,
                                                  int* __restrict__ ovfcnt,
                                                  const float* __restrict__ ea,
                                                  ushort* __restrict__ eab) {
    const int gtid = blockIdx.x * blockDim.x + threadIdx.x;
    const int stride = gridDim.x * blockDim.x;

    // ---- phase 1: bucket scatter of {row, e} ----
    for (int e = gtid; e < N_EDGES; e += stride) {
        const int c = col[e];
        const int r = row[e];
        const int pos = atomicAdd(&cursor[c], 1);
        if (pos < CAP) {
            erec[(size_t)c * CAP + pos] = make_int2(r, e);
        } else {
            const int o = atomicAdd(ovfcnt, 1);
            if (o < OVF_CAP) ovf[o] = make_int4(c, r, e, 0);
        }
    }

    // ---- phase 2: stream-convert ea (f32) -> eab (bf16), edge order ----
    const float4* s4 = (const float4*)ea;
    uint2* d2 = (uint2*)eab;
    const int NQ = N_EDGES * ED / 4;   // 10,000,000
    for (int k = gtid; k < NQ; k += stride) {
        const float4 v = s4[k];
        d2[k] = make_uint2(pk(v.x, v.y), pk(v.z, v.w));
    }
}

// ---------------- xl16 = bf16(x @ lw^T) (blocks 0..1023) | Cmat,lwb (block 1024) ----------------

__global__ void __launch_bounds__(256) xl16_combine_k(const float* __restrict__ x,
                                                      const float* __restrict__ lw,
                                                      ushort* __restrict__ xl,
                                                      const float* __restrict__ ew,
                                                      const float* __restrict__ eb,
                                                      float* __restrict__ Cmat,
                                                      float* __restrict__ lwb) {
    const int bid = blockIdx.x;
    if (bid < 1024) {
        const int lane = threadIdx.x & 63;
        const int wid  = bid * 4 + (threadIdx.x >> 6);
        const int nw   = 1024 * 4;

        float w[D];
        const float4* lw4 = (const float4*)(lw + (size_t)lane * D);
#pragma unroll
        for (int q = 0; q < D / 4; ++q) {
            const float4 v = lw4[q];
            w[4*q+0] = v.x; w[4*q+1] = v.y; w[4*q+2] = v.z; w[4*q+3] = v.w;
        }
        for (int n = wid; n < N_NODES; n += nw) {
            const float4* xx = (const float4*)(x + (size_t)n * D);
            float d0 = 0.f, d1 = 0.f;
#pragma unroll
            for (int q = 0; q < D / 8; ++q) {
                const float4 v0 = xx[q];
                const float4 v1 = xx[q + 8];
                d0 = fmaf(v0.x, w[4*q+0], d0);  d0 = fmaf(v0.y, w[4*q+1], d0);
                d0 = fmaf(v0.z, w[4*q+2], d0);  d0 = fmaf(v0.w, w[4*q+3], d0);
                d1 = fmaf(v1.x, w[4*q+32], d1); d1 = fmaf(v1.y, w[4*q+33], d1);
                d1 = fmaf(v1.z, w[4*q+34], d1); d1 = fmaf(v1.w, w[4*q+35], d1);
            }
            xl[(size_t)n * D + lane] = (ushort)bfr(d0 + d1);
        }
    } else {
        for (int idx = threadIdx.x; idx < D * ED; idx += 256) {
            const int d = idx >> 5, j = idx & 31;
            float s = 0.f;
#pragma unroll
            for (int k = 0; k < D; ++k) s = fmaf(lw[d * D + k], ew[k * ED + j], s);
            Cmat[idx] = s;
        }
        if (threadIdx.x < D) {
            float s = 0.f;
#pragma unroll
            for (int k = 0; k < D; ++k) s = fmaf(lw[threadIdx.x * D + k], eb[k], s);
            lwb[threadIdx.x] = s;
        }
    }
}

// ---------------- aggregation + epilogue (bf16 ea, quarter-wave; 1 node/wave-iter) ----------------
// out[n][d] = inv*( segsum(xl[row]) + Cmat·segsum(ea) )[d] + [deg>0]*lwb[d] + lb[d]

__global__ void __launch_bounds__(256) agg_v3_k(const ushort* __restrict__ xl,
                                                const ushort* __restrict__ eab,
                                                const int* __restrict__ deg_,
                                                const int2* __restrict__ erec,
                                                const int4* __restrict__ ovf,
                                                const int* __restrict__ ovfcnt,
                                                const float* __restrict__ Cmat,
                                                const float* __restrict__ lwb,
                                                const float* __restrict__ lb,
                                                float* __restrict__ out) {
    const int lane = threadIdx.x & 63;
    const int sub  = lane & 15;       // dim-pair index (dims 2*sub, 2*sub+1)
    const int g    = lane >> 4;       // edge group 0..3
    const int wid  = blockIdx.x * (blockDim.x >> 6) + (threadIdx.x >> 6);
    const int nw   = gridDim.x * (blockDim.x >> 6);

    const float lwbl = lwb[lane];
    const float lbl  = lb[lane];
    float w[ED];                      // Cmat row for this lane's output dim
    const float4* cm4 = (const float4*)(Cmat + (size_t)lane * ED);
#pragma unroll
    for (int q = 0; q < ED / 4; ++q) {
        const float4 v = cm4[q];
        w[4*q+0] = v.x; w[4*q+1] = v.y; w[4*q+2] = v.z; w[4*q+3] = v.w;
    }
    const int novf = min(*ovfcnt, OVF_CAP);

    for (int n = wid; n < N_NODES; n += nw) {
        const int deg  = deg_[n];
        const int degb = min(deg, CAP);
        float ax[8] = {0,0,0,0,0,0,0,0};
        float ael[4] = {0,0,0,0}, aeh[4] = {0,0,0,0};

        if (degb > 0) {
            const int2 rec = erec[(size_t)n * CAP + min(lane, degb - 1)];  // coalesced 256B

            // ---- xl gathers: unpredicated full rounds + predicated tail ----
            const int full = degb & ~7;
            for (int k = 0; k < full; k += 8) {
                float vx[8];
#pragma unroll
                for (int i = 0; i < 8; ++i)
                    vx[i] = bfu(xl[(size_t)__shfl(rec.x, k + i) * D + lane]);
#pragma unroll
                for (int i = 0; i < 8; ++i) ax[i] += vx[i];
            }
            if (full < degb) {
                float vx[8];
#pragma unroll
                for (int i = 0; i < 8; ++i)
                    vx[i] = bfu(xl[(size_t)__shfl(rec.x, min(full + i, degb - 1)) * D + lane]);
#pragma unroll
                for (int i = 0; i < 8; ++i) ax[i] += (full + i < degb) ? vx[i] : 0.f;
            }

            // ---- eab reads: quarter-wave per edge (4 edges/instr), single round (CAP=32) ----
            const int nq = (degb + 3) >> 2;        // <= 8
            {
                uint v[8];
                int pv[8];
#pragma unroll
                for (int i = 0; i < 8; ++i) {
                    const int s  = i * 4 + g;
                    const int e0 = __shfl(rec.y, min(s, degb - 1));
                    pv[i] = (i < nq) && (s < degb);
                    v[i] = *(const uint*)(eab + (size_t)e0 * ED + sub * 2);
                }
#pragma unroll
                for (int i = 0; i < 8; ++i) {
                    ael[i & 3] += pv[i] ? bflo(v[i]) : 0.f;
                    aeh[i & 3] += pv[i] ? bfhi(v[i]) : 0.f;
                }
            }
        }

        // ---- overflow edges (correctness path; empty in practice) ----
        if (novf > 0) {
            for (int o = 0; o < novf; ++o) {
                const int4 v = ovf[o];
                if (v.x == n) {
                    ax[0] += bfu(xl[(size_t)v.y * D + lane]);
                    if (lane < 16) {
                        const uint u = *(const uint*)(eab + (size_t)v.z * ED + sub * 2);
                        ael[0] += bflo(u); aeh[0] += bfhi(u);
                    }
                }
            }
        }

        float axs = ((ax[0]+ax[1])+(ax[2]+ax[3])) + ((ax[4]+ax[5])+(ax[6]+ax[7]));
        float sl = (ael[0]+ael[1]) + (ael[2]+ael[3]);
        float sh = (aeh[0]+aeh[1]) + (aeh[2]+aeh[3]);
        sl += __shfl_xor(sl, 16); sl += __shfl_xor(sl, 32);  // sum the 4 edge groups
        sh += __shfl_xor(sh, 16); sh += __shfl_xor(sh, 32);
        // lane with sub=s holds segsum(ea)[n][2s] (sl) and [2s+1] (sh)

        float zd = axs;
#pragma unroll
        for (int s = 0; s < 16; ++s) {
            zd = fmaf(__shfl(sl, s), w[2*s],   zd);
            zd = fmaf(__shfl(sh, s), w[2*s+1], zd);
        }
        const float inv = 1.f / fmaxf((float)deg, 1.f);
        out[(size_t)n * D + lane] = fmaf(inv, zd, (deg > 0 ? lwbl : 0.f) + lbl);
    }
}

// ---------------- tier C (tiny ws): atomic version ----------------

__global__ void __launch_bounds__(256) edge_scatter_fb(
    const float* __restrict__ x, const int* __restrict__ ei,
    const float* __restrict__ ea, const float* __restrict__ ew,
    const float* __restrict__ eb, float* __restrict__ agg, float* __restrict__ deg) {
    const int lane = threadIdx.x & 63;
    const int wid  = blockIdx.x * (blockDim.x >> 6) + (threadIdx.x >> 6);
    const int nw   = gridDim.x * (blockDim.x >> 6);
    float w[ED];
#pragma unroll
    for (int k = 0; k < ED; ++k) w[k] = ew[lane * ED + k];
    const float b = eb[lane];
    for (int e = wid; e < N_EDGES; e += nw) {
        const int r = ei[e];
        const int c = ei[N_EDGES + e];
        const float4* ea4 = (const float4*)(ea + (size_t)e * ED);
        float acc = b;
#pragma unroll
        for (int q = 0; q < ED / 4; ++q) {
            float4 v = ea4[q];
            acc = fmaf(v.x, w[4*q+0], acc); acc = fmaf(v.y, w[4*q+1], acc);
            acc = fmaf(v.z, w[4*q+2], acc); acc = fmaf(v.w, w[4*q+3], acc);
        }
        acc += x[(size_t)r * D + lane];
        atomicAdd(&agg[(size_t)c * D + lane], acc);
        if (lane == 0) atomicAdd(&deg[c], 1.0f);
    }
}

__global__ void __launch_bounds__(256) node_linear_fb(
    float* __restrict__ agg, const float* __restrict__ deg,
    const float* __restrict__ lw, const float* __restrict__ lb) {
    const int lane = threadIdx.x & 63;
    const int wid  = blockIdx.x * (blockDim.x >> 6) + (threadIdx.x >> 6);
    const int nw   = gridDim.x * (blockDim.x >> 6);
    float w[D];
#pragma unroll
    for (int k = 0; k < D; ++k) w[k] = lw[lane * D + k];
    const float b = lb[lane];
    for (int n = wid; n < N_NODES; n += nw) {
        const float inv = 1.0f / fmaxf(deg[n], 1.0f);
        const float4* a4 = (const float4*)(agg + (size_t)n * D);
        float dot = 0.0f;
#pragma unroll
        for (int q = 0; q < D / 4; ++q) {
            float4 v = a4[q];
            dot = fmaf(v.x, w[4*q+0], dot); dot = fmaf(v.y, w[4*q+1], dot);
            dot = fmaf(v.z, w[4*q+2], dot); dot = fmaf(v.w, w[4*q+3], dot);
        }
        agg[(size_t)n * D + lane] = fmaf(inv, dot, b);
    }
}

// ---------------- launch ----------------

extern "C" void kernel_launch(void* const* d_in, const int* in_sizes, int n_in,
                              void* d_out, int out_size, void* d_ws, size_t ws_size,
                              hipStream_t stream) {
    const float* x  = (const float*)d_in[0];
    const int*   ei = (const int*)d_in[1];     // [2][E]: rows then cols
    const float* ea = (const float*)d_in[2];
    const float* lw = (const float*)d_in[3];
    const float* lb = (const float*)d_in[4];
    const float* ew = (const float*)d_in[5];
    const float* eb = (const float*)d_in[6];
    const int* row = ei;
    const int* col = ei + N_EDGES;

    char* ws = (char*)d_ws;
    float* zout = (float*)d_out;

    // ws layout (~121.5 MB; tier-A ~127 MB was proven available in R9)
    const size_t W_EREC = 0;                                   // N*CAP int2 = 25,600,000
    const size_t W_EAB  = (size_t)N_NODES * CAP * 8;           // E*32 bf16  = 80,000,000
    const size_t W_XL   = W_EAB + (size_t)N_EDGES * ED * 2;    // N*64 bf16  = 12,800,000
    const size_t W_CNT  = W_XL + (size_t)N_NODES * D * 2;      //    400,000
    const size_t W_OVFC = W_CNT + (size_t)N_NODES * 4;         //         16
    const size_t W_OVF  = W_OVFC + 16;                         //  2,097,152
    const size_t W_CMAT = W_OVF + (size_t)OVF_CAP * 16;        //      8,192
    const size_t W_LWB  = W_CMAT + D * ED * 4;                 //        256
    const size_t REQ    = W_LWB + D * 4;

    if (ws_size >= REQ) {
        int2*   erec = (int2*)(ws + W_EREC);
        ushort* eab  = (ushort*)(ws + W_EAB);
        ushort* xl   = (ushort*)(ws + W_XL);
        int*    cnt  = (int*)(ws + W_CNT);
        int*    ovfc = (int*)(ws + W_OVFC);
        int4*   ovf  = (int4*)(ws + W_OVF);
        float*  Cmat = (float*)(ws + W_CMAT);
        float*  lwbv = (float*)(ws + W_LWB);

        hipMemsetAsync(cnt, 0, (size_t)N_NODES * sizeof(int) + 16, stream);
        scatconv_k     <<<2048, 256, 0, stream>>>(row, col, cnt, erec, ovf, ovfc, ea, eab);
        xl16_combine_k <<<1025, 256, 0, stream>>>(x, lw, xl, ew, eb, Cmat, lwbv);
        agg_v3_k       <<<4096, 256, 0, stream>>>(xl, eab, cnt, erec, ovf, ovfc,
                                                  Cmat, lwbv, lb, zout);
    } else {
        float* deg = (float*)d_ws;
        hipMemsetAsync(zout, 0, (size_t)N_NODES * D * sizeof(float), stream);
        hipMemsetAsync(deg, 0, (size_t)N_NODES * sizeof(float), stream);
        edge_scatter_fb<<<2048, 256, 0, stream>>>(x, ei, ea, ew, eb, zout, deg);
        node_linear_fb <<<1024, 256, 0, stream>>>(zout, deg, lw, lb);
    }
}

// Round 12
// 245.274 us; speedup vs baseline: 1.3367x; 1.2884x over previous
//
#include <hip/hip_runtime.h>

#define N_NODES 100000
#define N_EDGES 1250000
#define D 64
#define ED 32
#define CAP 32          // bucket = 32 slots * 8B = 256B line-aligned; P(deg>32)~7e-7/node (handled)
#define OVF_CAP 131072

typedef unsigned int uint;
typedef unsigned short ushort;

__device__ __forceinline__ uint bfr(float f) {
    uint u = __float_as_uint(f);
    return (u + 0x7FFFu + ((u >> 16) & 1u)) >> 16;
}
__device__ __forceinline__ float bflo(uint v) { return __uint_as_float(v << 16); }
__device__ __forceinline__ float bfhi(uint v) { return __uint_as_float(v & 0xffff0000u); }
__device__ __forceinline__ float bfu(ushort s) { return __uint_as_float(((uint)s) << 16); }

// ---------------- bucket scatter: erec[c*32+pos] = {row, e}; overflow to list ----------------

__global__ void __launch_bounds__(256) scatter_bucket_k(const int* __restrict__ row,
                                                        const int* __restrict__ col,
                                                        int* __restrict__ cursor,   // zeroed; becomes deg
                                                        int2* __restrict__ erec,
                                                        int4* __restrict__ ovf,
                                                        int* __restrict__ ovfcnt) {
    int i = blockIdx.x * blockDim.x + threadIdx.x;
    const int stride = gridDim.x * blockDim.x;
    for (int e = i; e < N_EDGES; e += stride) {
        const int c = col[e];
        const int r = row[e];
        const int pos = atomicAdd(&cursor[c], 1);
        if (pos < CAP) {
            erec[((size_t)c << 5) + pos] = make_int2(r, e);
        } else {
            const int o = atomicAdd(ovfcnt, 1);
            if (o < OVF_CAP) ovf[o] = make_int4(c, r, e, 0);
        }
    }
}

// ---------------- xl16 = bf16(x @ lw^T) (blocks 0..1023) | Cmat,lwb (block 1024) ----------------

__global__ void __launch_bounds__(256) xl16_combine_k(const float* __restrict__ x,
                                                      const float* __restrict__ lw,
                                                      ushort* __restrict__ xl,
                                                      const float* __restrict__ ew,
                                                      const float* __restrict__ eb,
                                                      float* __restrict__ Cmat,
                                                      float* __restrict__ lwb) {
    const int bid = blockIdx.x;
    if (bid < 1024) {
        const int lane = threadIdx.x & 63;
        const int wid  = bid * 4 + (threadIdx.x >> 6);
        const int nw   = 1024 * 4;

        float w[D];
        const float4* lw4 = (const float4*)(lw + (size_t)lane * D);
#pragma unroll
        for (int q = 0; q < D / 4; ++q) {
            const float4 v = lw4[q];
            w[4*q+0] = v.x; w[4*q+1] = v.y; w[4*q+2] = v.z; w[4*q+3] = v.w;
        }
        for (int n = wid; n < N_NODES; n += nw) {
            const float4* xx = (const float4*)(x + (size_t)n * D);
            float d0 = 0.f, d1 = 0.f;
#pragma unroll
            for (int q = 0; q < D / 8; ++q) {
                const float4 v0 = xx[q];
                const float4 v1 = xx[q + 8];
                d0 = fmaf(v0.x, w[4*q+0], d0);  d0 = fmaf(v0.y, w[4*q+1], d0);
                d0 = fmaf(v0.z, w[4*q+2], d0);  d0 = fmaf(v0.w, w[4*q+3], d0);
                d1 = fmaf(v1.x, w[4*q+32], d1); d1 = fmaf(v1.y, w[4*q+33], d1);
                d1 = fmaf(v1.z, w[4*q+34], d1); d1 = fmaf(v1.w, w[4*q+35], d1);
            }
            xl[(size_t)n * D + lane] = (ushort)bfr(d0 + d1);
        }
    } else {
        for (int idx = threadIdx.x; idx < D * ED; idx += 256) {
            const int d = idx >> 5, j = idx & 31;
            float s = 0.f;
#pragma unroll
            for (int k = 0; k < D; ++k) s = fmaf(lw[d * D + k], ew[k * ED + j], s);
            Cmat[idx] = s;
        }
        if (threadIdx.x < D) {
            float s = 0.f;
#pragma unroll
            for (int k = 0; k < D; ++k) s = fmaf(lw[threadIdx.x * D + k], eb[k], s);
            lwb[threadIdx.x] = s;
        }
    }
}

// ---------------- aggregation + epilogue v5 ----------------
// out[n][d] = inv*( segsum(xl[row]) + Cmat·segsum(ea) )[d] + [deg>0]*lwb[d] + lb[d]
// Packed xl reads (2 rows/instr, half-wave each) and interleaved xl||ea rounds:
// 16 cache-lines in flight per round, <=2 rounds (CAP=32), static-indexed accumulators.

__global__ void __launch_bounds__(256) agg_v5_k(const ushort* __restrict__ xl,
                                                const float* __restrict__ ea,
                                                const int* __restrict__ deg_,
                                                const int2* __restrict__ erec,
                                                const int4* __restrict__ ovf,
                                                const int* __restrict__ ovfcnt,
                                                const float* __restrict__ Cmat,
                                                const float* __restrict__ lwb,
                                                const float* __restrict__ lb,
                                                float* __restrict__ out) {
    const int lane = threadIdx.x & 63;
    const int half = lane >> 5;       // 0 or 1: which of the 2 rows this instr covers
    const int s31  = lane & 31;
    const int wid  = blockIdx.x * (blockDim.x >> 6) + (threadIdx.x >> 6);
    const int nw   = gridDim.x * (blockDim.x >> 6);

    const float lwbl = lwb[lane];
    const float lbl  = lb[lane];
    const float4* cm4 = (const float4*)(Cmat + (size_t)lane * ED);  // L1-hot
    const int novf = min(*ovfcnt, OVF_CAP);

    for (int n = wid; n < N_NODES; n += nw) {
        const int deg  = deg_[n];
        const int degb = min(deg, CAP);

        // packed xl accumulators: lane (either half) holds dims {2*s31, 2*s31+1}
        float axl = 0.f, axh = 0.f;
        float ae[4] = {0.f, 0.f, 0.f, 0.f};   // ea dim s31, this half's rows

        if (degb > 0) {
            // both halves hold slots 0..31 (256B bucket, broadcast within L1)
            const int2 rec = erec[((size_t)n << 5) + min(s31, degb - 1)];

            for (int base = 0; base < degb; base += 16) {   // <= 2 wave-uniform iters
                uint  vx[8];
                float ve[8];
#pragma unroll
                for (int i = 0; i < 8; ++i) {               // xl: rows base+2i+half
                    const int r = base + 2 * i + half;
                    const int nsrc = __shfl(rec.x, min(r, degb - 1));
                    vx[i] = *(const uint*)(xl + (size_t)nsrc * D + s31 * 2);
                }
#pragma unroll
                for (int i = 0; i < 8; ++i) {               // ea: rows base+2i+half
                    const int r = base + 2 * i + half;
                    const int esrc = __shfl(rec.y, min(r, degb - 1));
                    ve[i] = ea[(size_t)esrc * ED + s31];
                }
#pragma unroll
                for (int i = 0; i < 8; ++i) {
                    const bool p = (base + 2 * i + half) < degb;
                    axl += p ? bflo(vx[i]) : 0.f;
                    axh += p ? bfhi(vx[i]) : 0.f;
                }
#pragma unroll
                for (int i = 0; i < 8; ++i) {
                    const bool p = (base + 2 * i + half) < degb;
                    ae[i & 3] += p ? ve[i] : 0.f;
                }
            }
        }

        // ---- overflow edges (correctness path; empty in practice); half 0 adds once ----
        if (novf > 0) {
            for (int o = 0; o < novf; ++o) {
                const int4 v = ovf[o];
                if (v.x == n && half == 0) {
                    const uint u = *(const uint*)(xl + (size_t)v.y * D + s31 * 2);
                    axl += bflo(u); axh += bfhi(u);
                    ae[0] += ea[(size_t)v.z * ED + s31];
                }
            }
        }

        // ---- combine the two halves ----
        axl += __shfl_xor(axl, 32);           // full segsum(xl)[n][2*s31]
        axh += __shfl_xor(axh, 32);           // full segsum(xl)[n][2*s31+1]
        float aes = (ae[0] + ae[1]) + (ae[2] + ae[3]);
        aes += __shfl_xor(aes, 32);           // full segsum(ea)[n][s31]

        // repack xl sums: lane d needs dim d = pair d>>1, lo/hi by d&1
        const float a0 = __shfl(axl, lane >> 1);
        const float a1 = __shfl(axh, lane >> 1);
        float zd = (lane & 1) ? a1 : a0;

#pragma unroll
        for (int q = 0; q < ED / 4; ++q) {
            const float4 wv = cm4[q];
            zd = fmaf(__shfl(aes, 4*q+0), wv.x, zd);
            zd = fmaf(__shfl(aes, 4*q+1), wv.y, zd);
            zd = fmaf(__shfl(aes, 4*q+2), wv.z, zd);
            zd = fmaf(__shfl(aes, 4*q+3), wv.w, zd);
        }
        const float inv = 1.f / fmaxf((float)deg, 1.f);
        out[(size_t)n * D + lane] = fmaf(inv, zd, (deg > 0 ? lwbl : 0.f) + lbl);
    }
}

// ---------------- tier C (tiny ws): atomic version ----------------

__global__ void __launch_bounds__(256) edge_scatter_fb(
    const float* __restrict__ x, const int* __restrict__ ei,
    const float* __restrict__ ea, const float* __restrict__ ew,
    const float* __restrict__ eb, float* __restrict__ agg, float* __restrict__ deg) {
    const int lane = threadIdx.x & 63;
    const int wid  = blockIdx.x * (blockDim.x >> 6) + (threadIdx.x >> 6);
    const int nw   = gridDim.x * (blockDim.x >> 6);
    float w[ED];
#pragma unroll
    for (int k = 0; k < ED; ++k) w[k] = ew[lane * ED + k];
    const float b = eb[lane];
    for (int e = wid; e < N_EDGES; e += nw) {
        const int r = ei[e];
        const int c = ei[N_EDGES + e];
        const float4* ea4 = (const float4*)(ea + (size_t)e * ED);
        float acc = b;
#pragma unroll
        for (int q = 0; q < ED / 4; ++q) {
            float4 v = ea4[q];
            acc = fmaf(v.x, w[4*q+0], acc); acc = fmaf(v.y, w[4*q+1], acc);
            acc = fmaf(v.z, w[4*q+2], acc); acc = fmaf(v.w, w[4*q+3], acc);
        }
        acc += x[(size_t)r * D + lane];
        atomicAdd(&agg[(size_t)c * D + lane], acc);
        if (lane == 0) atomicAdd(&deg[c], 1.0f);
    }
}

__global__ void __launch_bounds__(256) node_linear_fb(
    float* __restrict__ agg, const float* __restrict__ deg,
    const float* __restrict__ lw, const float* __restrict__ lb) {
    const int lane = threadIdx.x & 63;
    const int wid  = blockIdx.x * (blockDim.x >> 6) + (threadIdx.x >> 6);
    const int nw   = gridDim.x * (blockDim.x >> 6);
    float w[D];
#pragma unroll
    for (int k = 0; k < D; ++k) w[k] = lw[lane * D + k];
    const float b = lb[lane];
    for (int n = wid; n < N_NODES; n += nw) {
        const float inv = 1.0f / fmaxf(deg[n], 1.0f);
        const float4* a4 = (const float4*)(agg + (size_t)n * D);
        float dot = 0.0f;
#pragma unroll
        for (int q = 0; q < D / 4; ++q) {
            float4 v = a4[q];
            dot = fmaf(v.x, w[4*q+0], dot); dot = fmaf(v.y, w[4*q+1], dot);
            dot = fmaf(v.z, w[4*q+2], dot); dot = fmaf(v.w, w[4*q+3], dot);
        }
        agg[(size_t)n * D + lane] = fmaf(inv, dot, b);
    }
}

// ---------------- launch ----------------

extern "C" void kernel_launch(void* const* d_in, const int* in_sizes, int n_in,
                              void* d_out, int out_size, void* d_ws, size_t ws_size,
                              hipStream_t stream) {
    const float* x  = (const float*)d_in[0];
    const int*   ei = (const int*)d_in[1];     // [2][E]: rows then cols
    const float* ea = (const float*)d_in[2];
    const float* lw = (const float*)d_in[3];
    const float* lb = (const float*)d_in[4];
    const float* ew = (const float*)d_in[5];
    const float* eb = (const float*)d_in[6];
    const int* row = ei;
    const int* col = ei + N_EDGES;

    char* ws = (char*)d_ws;
    float* zout = (float*)d_out;

    // ws layout (~41 MB)
    const size_t W_EREC = 0;                                   // N*32 int2 = 25,600,000
    const size_t W_XL   = (size_t)N_NODES * CAP * 8;           // N*64 bf16 = 12,800,000
    const size_t W_CNT  = W_XL + (size_t)N_NODES * D * 2;      //    400,000
    const size_t W_OVFC = W_CNT + (size_t)N_NODES * 4;         //         16
    const size_t W_OVF  = W_OVFC + 16;                         //  2,097,152
    const size_t W_CMAT = W_OVF + (size_t)OVF_CAP * 16;        //      8,192
    const size_t W_LWB  = W_CMAT + D * ED * 4;                 //        256
    const size_t REQ    = W_LWB + D * 4;

    if (ws_size >= REQ) {
        int2*   erec = (int2*)(ws + W_EREC);
        ushort* xl   = (ushort*)(ws + W_XL);
        int*    cnt  = (int*)(ws + W_CNT);
        int*    ovfc = (int*)(ws + W_OVFC);
        int4*   ovf  = (int4*)(ws + W_OVF);
        float*  Cmat = (float*)(ws + W_CMAT);
        float*  lwbv = (float*)(ws + W_LWB);

        hipMemsetAsync(cnt, 0, (size_t)N_NODES * sizeof(int) + 16, stream);
        scatter_bucket_k<<<2048, 256, 0, stream>>>(row, col, cnt, erec, ovf, ovfc);
        xl16_combine_k  <<<1025, 256, 0, stream>>>(x, lw, xl, ew, eb, Cmat, lwbv);
        agg_v5_k        <<<4096, 256, 0, stream>>>(xl, ea, cnt, erec, ovf, ovfc,
                                                   Cmat, lwbv, lb, zout);
    } else {
        float* deg = (float*)d_ws;
        hipMemsetAsync(zout, 0, (size_t)N_NODES * D * sizeof(float), stream);
        hipMemsetAsync(deg, 0, (size_t)N_NODES * sizeof(float), stream);
        edge_scatter_fb<<<2048, 256, 0, stream>>>(x, ei, ea, ew, eb, zout, deg);
        node_linear_fb <<<1024, 256, 0, stream>>>(zout, deg, lw, lb);
    }
}